// Round 1
// baseline (95.707 us; speedup 1.0000x reference)
//
#include <hip/hip_runtime.h>
#include <math.h>
#include <limits.h>

#define SIZE   256
#define NFACES 256
#define NVERTS 1024

// LDS face record, 5 x float4 per face:
// q0: ax ay bx by | q1: cx cy xmin xmax | q2: z0i z1i z2i A
// q3: u0x u0y u1x u1y | q4: u2x u2y 0 0

// grid (256): one block per row, 256 threads = one thread per pixel.
// Phase 1 (all 256 threads): prep face t (1:1), cull A<1e-9 (=> cover false
//   exactly) and y-bbox vs this row with 1e-4 margin (fp edge noise
//   <= ~5e-7*scale, cannot flip the reference sign test; validated in prior
//   session R4). Stable ballot compaction keeps ascending face order.
// Phase 2: every thread walks the full compacted list for its own column with
//   wave-uniform x-bbox cull (wave = 64 contiguous columns, same margin).
//   Ascending face id + strict > == numpy argmax first-max; no cross-group
//   combine phase needed.
// Epilogue: same thread does its own pixel's bilinear sample — all 256 lanes
//   active, coalesced stores. 2 barriers total (was 3 + combine round-trip).
__global__ __launch_bounds__(256) void render_kernel(
    const float* __restrict__ vertices,  // (1024,3)
    const int*   __restrict__ faces,     // (256,3)
    const float* __restrict__ uv,        // (1024,2)
    const int*   __restrict__ uvfaces,   // (256,3)
    const float* __restrict__ uvmap,     // (3,256,256)
    float* __restrict__ out)             // (4,256,256)
{
#pragma clang fp contract(off)
    __shared__ float4 fdl[NFACES * 5];
    __shared__ int    sfid[NFACES];
    __shared__ float  wred[4];
    __shared__ int    wcnt[4];

    const int t    = threadIdx.x;        // 0..255 == column
    const int lane = t & 63;
    const int wv   = t >> 6;             // wave 0..3
    const int row  = blockIdx.x;         // 0..255
    const int col  = t;

    // pts[i,j] = (lin[j], lin[255-i]); linspace f64 -> f32 (numpy style)
    const float px = (float)(-1.0 + (double)col         * (2.0/255.0));
    const float py = (float)(-1.0 + (double)(255 - row) * (2.0/255.0));

    // ---- zinit partial: each thread takes 4 vertex z, wave-min via shfl ----
    {
        float m =       vertices[3*t        + 2];
        m = fminf(m,    vertices[3*(t+256)  + 2]);
        m = fminf(m,    vertices[3*(t+512)  + 2]);
        m = fminf(m,    vertices[3*(t+768)  + 2]);
        for (int off = 32; off > 0; off >>= 1) m = fminf(m, __shfl_down(m, off));
        if (lane == 0) wred[wv] = m;
    }

    // ---- per-face prep in registers: thread t handles face t (1:1) ----
    float4 q0, q1, q2, q3, q4;
    bool keep = false;
    int  rank = 0;
    {
        const int i0 = faces[3*t+0], i1 = faces[3*t+1], i2 = faces[3*t+2];
        const float ax = vertices[3*i0+0], ay = vertices[3*i0+1], az = vertices[3*i0+2];
        const float bx = vertices[3*i1+0], by = vertices[3*i1+1], bz = vertices[3*i1+2];
        const float cx = vertices[3*i2+0], cy = vertices[3*i2+1], cz = vertices[3*i2+2];
        // A = area2d; same fp32 expression as face-normal z =>
        // cullmask & (A>=1e-9) == (A>=1e-9); A>=1e-9 also => Asafe==A
        const float A = (bx-ax)*(cy-ay) - (by-ay)*(cx-ax);
        const float ymin = fminf(fminf(ay,by),cy);
        const float ymax = fmaxf(fmaxf(ay,by),cy);
        keep = (A >= 1e-9f) && (py > ymin - 1e-4f) && (py < ymax + 1e-4f);
        const unsigned long long bmask = __ballot(keep);
        rank = __popcll(bmask & ((1ull << lane) - 1ull));
        if (lane == 0) wcnt[wv] = (int)__popcll(bmask);
        if (keep) {
            const float z0i = 1.0f/az, z1i = 1.0f/bz, z2i = 1.0f/cz;
            const int j0 = uvfaces[3*t+0], j1 = uvfaces[3*t+1], j2 = uvfaces[3*t+2];
            q0 = make_float4(ax, ay, bx, by);
            q1 = make_float4(cx, cy, fminf(fminf(ax,bx),cx), fmaxf(fmaxf(ax,bx),cx));
            q2 = make_float4(z0i, z1i, z2i, A);
            q3 = make_float4((uv[2*j0+0]*2.0f - 1.0f) * z0i,
                             (uv[2*j0+1]*2.0f - 1.0f) * z0i,
                             (uv[2*j1+0]*2.0f - 1.0f) * z1i,
                             (uv[2*j1+1]*2.0f - 1.0f) * z1i);
            q4 = make_float4((uv[2*j2+0]*2.0f - 1.0f) * z2i,
                             (uv[2*j2+1]*2.0f - 1.0f) * z2i, 0.0f, 0.0f);
        }
    }
    __syncthreads();   // wred + wcnt published

    const float zinit = fminf(fminf(wred[0], wred[1]), fminf(wred[2], wred[3]));
    const int   nv    = wcnt[0] + wcnt[1] + wcnt[2] + wcnt[3];

    if (keep) {
        int base = 0;
        #pragma unroll
        for (int w = 0; w < 4; ++w) if (w < wv) base += wcnt[w];
        const int slot = base + rank;
        sfid[slot] = t;
        fdl[slot*5+0] = q0; fdl[slot*5+1] = q1; fdl[slot*5+2] = q2;
        fdl[slot*5+3] = q3; fdl[slot*5+4] = q4;
    }
    __syncthreads();   // fdl + sfid published

    // wave-uniform x-span (each wave = 64 contiguous columns)
    const int   c0   = wv * 64;
    const float pxlo = (float)(-1.0 + (double)c0        * (2.0/255.0));
    const float pxhi = (float)(-1.0 + (double)(c0 + 63) * (2.0/255.0));

    float best  = -INFINITY;
    int   wfid  = INT_MAX;
    int   wslot = 0;
    for (int i = 0; i < nv; ++i) {
        const float4 c1 = fdl[i*5+1];        // cx cy xmin xmax
        // wave-uniform x-bbox cull (1e-4 margin, validated in prior R4)
        if (c1.w + 1e-4f < pxlo || c1.z - 1e-4f > pxhi) continue;
        const float4 c0q = fdl[i*5+0];       // ax ay bx by
        const float pAB = (px - c0q.z)*(c0q.y - c0q.w) - (py - c0q.w)*(c0q.x - c0q.z);
        const float pCB = (px - c1.x)*(c0q.w - c1.y)   - (py - c1.y)*(c0q.z - c1.x);
        const float pCA = (px - c0q.x)*(c1.y - c0q.y)  - (py - c0q.y)*(c1.x - c0q.x);
        if (pAB > 0.0f && pCB > 0.0f && pCA > 0.0f) {
            const float4 c2 = fdl[i*5+2];    // z0i z1i z2i A
            const float w1 = pCB / c2.w;
            const float w2 = pCA / c2.w;
            const float w3 = (1.0f - w1) - w2;
            const float zp = (w1*c2.x + w2*c2.y) + w3*c2.z;
            const float z  = 1.0f / zp;                // ptsZ
            if (z >= zinit) {
                // ascending face id => strict > == argmax first-max;
                // tie-compare kept for safety (free)
                const int fid = sfid[i];
                if (z > best || (z == best && fid < wfid)) { best = z; wfid = fid; wslot = i; }
            }
        }
    }

    // ---- epilogue: every thread finishes its own pixel ----
    const bool  hit = (best > -INFINITY);
    const float hf  = hit ? 1.0f : 0.0f;
    float r0 = 0.0f, r1 = 0.0f, r2 = 0.0f;

    if (hit) {
        const float4 c0q = fdl[wslot*5+0];
        const float4 c1  = fdl[wslot*5+1];
        const float4 c2  = fdl[wslot*5+2];
        const float4 c3  = fdl[wslot*5+3];
        const float4 c4  = fdl[wslot*5+4];
        const float pCB = (px - c1.x)*(c0q.w - c1.y)  - (py - c1.y)*(c0q.z - c1.x);
        const float pCA = (px - c0q.x)*(c1.y - c0q.y) - (py - c0q.y)*(c1.x - c0q.x);
        const float w1 = pCB / c2.w;
        const float w2 = pCA / c2.w;
        const float w3 = (1.0f - w1) - w2;
        const float p3 = (w1*c3.x + w2*c3.z) + w3*c4.x;  // uv.x * zinv interp
        const float p4 = (w1*c3.y + w2*c3.w) + w3*c4.y;  // uv.y * zinv interp
        const float p8 = (w1*c2.x + w2*c2.y) + w3*c2.z;  // zinv interp
        const float Zw = 1.0f / p8;
        const float gx = p3 * Zw;
        const float gy = p4 * Zw;

        // bilinear_sample(uvmap, gx, gy), zero padding, W=H=256
        const float x = ((gx + 1.0f)*256.0f - 1.0f)*0.5f;
        const float y = ((gy + 1.0f)*256.0f - 1.0f)*0.5f;
        const float x0f = floorf(x), y0f = floorf(y);
        const float x1f = x0f + 1.0f, y1f = y0f + 1.0f;
        const float wx1 = x - x0f, wx0 = 1.0f - wx1;
        const float wy1 = y - y0f, wy0 = 1.0f - wy1;
        const float w00 = wx0*wy0, w10 = wx1*wy0, w01 = wx0*wy1, w11 = wx1*wy1;

        // corner order matches reference add order
        {
            const bool v = (x0f >= 0.0f) && (x0f <= 255.0f) && (y0f >= 0.0f) && (y0f <= 255.0f);
            const int ix = (int)fminf(fmaxf(x0f, 0.0f), 255.0f);
            const int iy = (int)fminf(fmaxf(y0f, 0.0f), 255.0f);
            const int o  = iy*256 + ix;
            const float g0 = v ? uvmap[o]          : 0.0f;
            const float g1 = v ? uvmap[65536 + o]  : 0.0f;
            const float g2 = v ? uvmap[131072 + o] : 0.0f;
            r0 = r0 + g0*w00; r1 = r1 + g1*w00; r2 = r2 + g2*w00;
        }
        {
            const bool v = (x1f >= 0.0f) && (x1f <= 255.0f) && (y0f >= 0.0f) && (y0f <= 255.0f);
            const int ix = (int)fminf(fmaxf(x1f, 0.0f), 255.0f);
            const int iy = (int)fminf(fmaxf(y0f, 0.0f), 255.0f);
            const int o  = iy*256 + ix;
            const float g0 = v ? uvmap[o]          : 0.0f;
            const float g1 = v ? uvmap[65536 + o]  : 0.0f;
            const float g2 = v ? uvmap[131072 + o] : 0.0f;
            r0 = r0 + g0*w10; r1 = r1 + g1*w10; r2 = r2 + g2*w10;
        }
        {
            const bool v = (x0f >= 0.0f) && (x0f <= 255.0f) && (y1f >= 0.0f) && (y1f <= 255.0f);
            const int ix = (int)fminf(fmaxf(x0f, 0.0f), 255.0f);
            const int iy = (int)fminf(fmaxf(y1f, 0.0f), 255.0f);
            const int o  = iy*256 + ix;
            const float g0 = v ? uvmap[o]          : 0.0f;
            const float g1 = v ? uvmap[65536 + o]  : 0.0f;
            const float g2 = v ? uvmap[131072 + o] : 0.0f;
            r0 = r0 + g0*w01; r1 = r1 + g1*w01; r2 = r2 + g2*w01;
        }
        {
            const bool v = (x1f >= 0.0f) && (x1f <= 255.0f) && (y1f >= 0.0f) && (y1f <= 255.0f);
            const int ix = (int)fminf(fmaxf(x1f, 0.0f), 255.0f);
            const int iy = (int)fminf(fmaxf(y1f, 0.0f), 255.0f);
            const int o  = iy*256 + ix;
            const float g0 = v ? uvmap[o]          : 0.0f;
            const float g1 = v ? uvmap[65536 + o]  : 0.0f;
            const float g2 = v ? uvmap[131072 + o] : 0.0f;
            r0 = r0 + g0*w11; r1 = r1 + g1*w11; r2 = r2 + g2*w11;
        }
    }

    const int pix = row*256 + col;
    out[           pix] = r0*hf;
    out[ 65536 +   pix] = r1*hf;
    out[131072 +   pix] = r2*hf;
    out[196608 +   pix] = hf;
}

extern "C" void kernel_launch(void* const* d_in, const int* in_sizes, int n_in,
                              void* d_out, int out_size, void* d_ws, size_t ws_size,
                              hipStream_t stream) {
    const float* vertices = (const float*)d_in[0];
    const int*   faces    = (const int*)  d_in[1];
    const float* uv       = (const float*)d_in[2];
    const int*   uvfaces  = (const int*)  d_in[3];
    const float* uvmap    = (const float*)d_in[4];
    float*       out      = (float*)d_out;

    dim3 grid(SIZE);
    render_kernel<<<grid, 256, 0, stream>>>(vertices, faces, uv, uvfaces, uvmap, out);
}

// Round 2
// 77.719 us; speedup vs baseline: 1.2315x; 1.2315x over previous
//
#include <hip/hip_runtime.h>
#include <math.h>
#include <limits.h>

#define SIZE   256
#define NFACES 256
#define NVERTS 1024
#define NSPLIT 4     // 4 face-groups of 256 columns each (block = 1024 threads)

// LDS face record, 5 x float4 per face:
// q0: ax ay bx by | q1: cx cy xmin xmax | q2: z0i z1i z2i A
// q3: u0x u0y u1x u1y | q4: u2x u2y 0 0

// grid (256): one block per ROW, 1024 threads = 4 face-groups x 256 columns.
// vs R0 (grid 2x256): same 16 waves/block for latency hiding, but face prep
// runs 256x instead of 512x, launch ramp halves, combine is 4-way not 8-way,
// epilogue uses 256 threads not 128. Loop goes 8 -> ~16 iters (cheap, LDS-fed,
// 4 waves/SIMD still hide it). vs R1 (the regression): waves/block stay 16,
// loop stays short -- R1's failure was 1 wave/SIMD + 64-iter serial LDS chain.
// Phase 1 (threads<256): prep face t, cull A<1e-9 (=> cover false exactly) and
//   y-bbox vs this row with 1e-4 margin (fp edge noise <= ~5e-7*scale, cannot
//   flip the reference sign test; validated prior session R4). Stable ballot
//   compaction keeps ascending face order.
// Phase 2: group g=t>>8 tests its chunk of the compacted list for column
//   t&255, with wave-uniform x-bbox cull (wave = 64 contiguous columns).
// Winner: max z, lowest face id on exact tie == numpy argmax first-max
// (chunks ascend in face id, combine ascends in group).
__global__ __launch_bounds__(1024) void render_kernel(
    const float* __restrict__ vertices,  // (1024,3)
    const int*   __restrict__ faces,     // (256,3)
    const float* __restrict__ uv,        // (1024,2)
    const int*   __restrict__ uvfaces,   // (256,3)
    const float* __restrict__ uvmap,     // (3,256,256)
    float* __restrict__ out)             // (4,256,256)
{
#pragma clang fp contract(off)
    __shared__ float4 fdl[NFACES * 5];
    __shared__ int    sfid[NFACES];
    __shared__ float  sh_best[NSPLIT][256];
    __shared__ int    sh_fid [NSPLIT][256];
    __shared__ int    sh_slot[NSPLIT][256];
    __shared__ float  wred[16];
    __shared__ int    wcnt[4];

    const int t    = threadIdx.x;
    const int lane = t & 63;
    const int wv   = t >> 6;                 // wave 0..15
    const int row  = blockIdx.x;             // 0..255
    const int col  = t & 255;                // column 0..255
    const int grp  = t >> 8;                 // face-group 0..3

    // pts[i,j] = (lin[j], lin[255-i]); linspace f64 -> f32 (numpy style)
    const float px = (float)(-1.0 + (double)col         * (2.0/255.0));
    const float py = (float)(-1.0 + (double)(255 - row) * (2.0/255.0));

    // ---- zinit partial: wave min of one vertex z per thread (1024 = NVERTS) ----
    {
        float m = vertices[3*t + 2];
        for (int off = 32; off > 0; off >>= 1) m = fminf(m, __shfl_down(m, off));
        if (lane == 0) wred[wv] = m;
    }

    // ---- per-face prep in registers: thread t < 256 handles face t ----
    float4 q0, q1, q2, q3, q4;
    bool keep = false;
    int  rank = 0;
    if (t < NFACES) {
        const int i0 = faces[3*t+0], i1 = faces[3*t+1], i2 = faces[3*t+2];
        const float ax = vertices[3*i0+0], ay = vertices[3*i0+1], az = vertices[3*i0+2];
        const float bx = vertices[3*i1+0], by = vertices[3*i1+1], bz = vertices[3*i1+2];
        const float cx = vertices[3*i2+0], cy = vertices[3*i2+1], cz = vertices[3*i2+2];
        // A = area2d; same fp32 expression as face-normal z =>
        // cullmask & (A>=1e-9) == (A>=1e-9); A>=1e-9 also => Asafe==A
        const float A = (bx-ax)*(cy-ay) - (by-ay)*(cx-ax);
        const float ymin = fminf(fminf(ay,by),cy);
        const float ymax = fmaxf(fmaxf(ay,by),cy);
        keep = (A >= 1e-9f) && (py > ymin - 1e-4f) && (py < ymax + 1e-4f);
        const unsigned long long bmask = __ballot(keep);
        rank = __popcll(bmask & ((1ull << lane) - 1ull));
        if (lane == 0) wcnt[wv] = (int)__popcll(bmask);
        if (keep) {
            const float z0i = 1.0f/az, z1i = 1.0f/bz, z2i = 1.0f/cz;
            const int j0 = uvfaces[3*t+0], j1 = uvfaces[3*t+1], j2 = uvfaces[3*t+2];
            const float2 u0 = *reinterpret_cast<const float2*>(&uv[2*j0]);
            const float2 u1 = *reinterpret_cast<const float2*>(&uv[2*j1]);
            const float2 u2 = *reinterpret_cast<const float2*>(&uv[2*j2]);
            q0 = make_float4(ax, ay, bx, by);
            q1 = make_float4(cx, cy, fminf(fminf(ax,bx),cx), fmaxf(fmaxf(ax,bx),cx));
            q2 = make_float4(z0i, z1i, z2i, A);
            q3 = make_float4((u0.x*2.0f - 1.0f) * z0i,
                             (u0.y*2.0f - 1.0f) * z0i,
                             (u1.x*2.0f - 1.0f) * z1i,
                             (u1.y*2.0f - 1.0f) * z1i);
            q4 = make_float4((u2.x*2.0f - 1.0f) * z2i,
                             (u2.y*2.0f - 1.0f) * z2i, 0.0f, 0.0f);
        }
    }
    __syncthreads();   // wred + wcnt published

    float zinit;
    {
        float mm = wred[0];
        #pragma unroll
        for (int i = 1; i < 16; ++i) mm = fminf(mm, wred[i]);
        zinit = mm;    // every thread computes; no extra barrier
    }
    const int nv = wcnt[0] + wcnt[1] + wcnt[2] + wcnt[3];

    if (t < NFACES && keep) {
        int base = 0;
        #pragma unroll
        for (int w = 0; w < 4; ++w) if (w < wv) base += wcnt[w];
        const int slot = base + rank;
        sfid[slot] = t;
        fdl[slot*5+0] = q0; fdl[slot*5+1] = q1; fdl[slot*5+2] = q2;
        fdl[slot*5+3] = q3; fdl[slot*5+4] = q4;
    }
    __syncthreads();   // fdl + sfid published

    // wave-uniform x-span (each wave = 64 contiguous columns)
    const int   c0   = ((t >> 6) & 3) * 64;
    const float pxlo = (float)(-1.0 + (double)c0        * (2.0/255.0));
    const float pxhi = (float)(-1.0 + (double)(c0 + 63) * (2.0/255.0));

    const int cs = (nv + NSPLIT - 1) / NSPLIT;
    int f0 = grp * cs; if (f0 > nv) f0 = nv;
    int f1 = f0 + cs;  if (f1 > nv) f1 = nv;

    float best  = -INFINITY;
    int   wfid  = INT_MAX;
    int   wslot = 0;
    for (int i = f0; i < f1; ++i) {
        const float4 c1 = fdl[i*5+1];        // cx cy xmin xmax
        // wave-uniform x-bbox cull (1e-4 margin, validated prior session R4)
        if (c1.w + 1e-4f < pxlo || c1.z - 1e-4f > pxhi) continue;
        const float4 c0q = fdl[i*5+0];       // ax ay bx by
        const float pAB = (px - c0q.z)*(c0q.y - c0q.w) - (py - c0q.w)*(c0q.x - c0q.z);
        const float pCB = (px - c1.x)*(c0q.w - c1.y)   - (py - c1.y)*(c0q.z - c1.x);
        const float pCA = (px - c0q.x)*(c1.y - c0q.y)  - (py - c0q.y)*(c1.x - c0q.x);
        if (pAB > 0.0f && pCB > 0.0f && pCA > 0.0f) {
            const float4 c2 = fdl[i*5+2];    // z0i z1i z2i A
            const float w1 = pCB / c2.w;
            const float w2 = pCA / c2.w;
            const float w3 = (1.0f - w1) - w2;
            const float zp = (w1*c2.x + w2*c2.y) + w3*c2.z;
            const float z  = 1.0f / zp;                // ptsZ
            if (z >= zinit) {
                const int fid = sfid[i];
                if (z > best || (z == best && fid < wfid)) { best = z; wfid = fid; wslot = i; }
            }
        }
    }
    sh_best[grp][col] = best;
    sh_fid [grp][col] = wfid;
    sh_slot[grp][col] = wslot;
    __syncthreads();

    // ---- combine 4 groups + epilogue: threads 0..255 (one per column) ----
    if (t < 256) {
        best = -INFINITY; wfid = INT_MAX; wslot = 0;
        #pragma unroll
        for (int g = 0; g < NSPLIT; ++g) {   // chunks ascend in face id; strict >
            const float z = sh_best[g][t];   // + fid tie-break == first-max
            const int   f = sh_fid [g][t];
            if (z > best || (z == best && f < wfid)) { best = z; wfid = f; wslot = sh_slot[g][t]; }
        }

        const bool  hit = (best > -INFINITY);
        const float hf  = hit ? 1.0f : 0.0f;
        float r0 = 0.0f, r1 = 0.0f, r2 = 0.0f;

        if (hit) {
            const float4 c0q = fdl[wslot*5+0];
            const float4 c1  = fdl[wslot*5+1];
            const float4 c2  = fdl[wslot*5+2];
            const float4 c3  = fdl[wslot*5+3];
            const float4 c4  = fdl[wslot*5+4];
            const float pCB = (px - c1.x)*(c0q.w - c1.y)  - (py - c1.y)*(c0q.z - c1.x);
            const float pCA = (px - c0q.x)*(c1.y - c0q.y) - (py - c0q.y)*(c1.x - c0q.x);
            const float w1 = pCB / c2.w;
            const float w2 = pCA / c2.w;
            const float w3 = (1.0f - w1) - w2;
            const float p3 = (w1*c3.x + w2*c3.z) + w3*c4.x;  // uv.x * zinv interp
            const float p4 = (w1*c3.y + w2*c3.w) + w3*c4.y;  // uv.y * zinv interp
            const float p8 = (w1*c2.x + w2*c2.y) + w3*c2.z;  // zinv interp
            const float Zw = 1.0f / p8;
            const float gx = p3 * Zw;
            const float gy = p4 * Zw;

            // bilinear_sample(uvmap, gx, gy), zero padding, W=H=256
            const float x = ((gx + 1.0f)*256.0f - 1.0f)*0.5f;
            const float y = ((gy + 1.0f)*256.0f - 1.0f)*0.5f;
            const float x0f = floorf(x), y0f = floorf(y);
            const float x1f = x0f + 1.0f, y1f = y0f + 1.0f;
            const float wx1 = x - x0f, wx0 = 1.0f - wx1;
            const float wy1 = y - y0f, wy0 = 1.0f - wy1;
            const float w00 = wx0*wy0, w10 = wx1*wy0, w01 = wx0*wy1, w11 = wx1*wy1;

            // corner order matches reference add order
            {
                const bool v = (x0f >= 0.0f) && (x0f <= 255.0f) && (y0f >= 0.0f) && (y0f <= 255.0f);
                const int ix = (int)fminf(fmaxf(x0f, 0.0f), 255.0f);
                const int iy = (int)fminf(fmaxf(y0f, 0.0f), 255.0f);
                const int o  = iy*256 + ix;
                const float g0 = v ? uvmap[o]          : 0.0f;
                const float g1 = v ? uvmap[65536 + o]  : 0.0f;
                const float g2 = v ? uvmap[131072 + o] : 0.0f;
                r0 = r0 + g0*w00; r1 = r1 + g1*w00; r2 = r2 + g2*w00;
            }
            {
                const bool v = (x1f >= 0.0f) && (x1f <= 255.0f) && (y0f >= 0.0f) && (y0f <= 255.0f);
                const int ix = (int)fminf(fmaxf(x1f, 0.0f), 255.0f);
                const int iy = (int)fminf(fmaxf(y0f, 0.0f), 255.0f);
                const int o  = iy*256 + ix;
                const float g0 = v ? uvmap[o]          : 0.0f;
                const float g1 = v ? uvmap[65536 + o]  : 0.0f;
                const float g2 = v ? uvmap[131072 + o] : 0.0f;
                r0 = r0 + g0*w10; r1 = r1 + g1*w10; r2 = r2 + g2*w10;
            }
            {
                const bool v = (x0f >= 0.0f) && (x0f <= 255.0f) && (y1f >= 0.0f) && (y1f <= 255.0f);
                const int ix = (int)fminf(fmaxf(x0f, 0.0f), 255.0f);
                const int iy = (int)fminf(fmaxf(y1f, 0.0f), 255.0f);
                const int o  = iy*256 + ix;
                const float g0 = v ? uvmap[o]          : 0.0f;
                const float g1 = v ? uvmap[65536 + o]  : 0.0f;
                const float g2 = v ? uvmap[131072 + o] : 0.0f;
                r0 = r0 + g0*w01; r1 = r1 + g1*w01; r2 = r2 + g2*w01;
            }
            {
                const bool v = (x1f >= 0.0f) && (x1f <= 255.0f) && (y1f >= 0.0f) && (y1f <= 255.0f);
                const int ix = (int)fminf(fmaxf(x1f, 0.0f), 255.0f);
                const int iy = (int)fminf(fmaxf(y1f, 0.0f), 255.0f);
                const int o  = iy*256 + ix;
                const float g0 = v ? uvmap[o]          : 0.0f;
                const float g1 = v ? uvmap[65536 + o]  : 0.0f;
                const float g2 = v ? uvmap[131072 + o] : 0.0f;
                r0 = r0 + g0*w11; r1 = r1 + g1*w11; r2 = r2 + g2*w11;
            }
        }

        const int pix = row*256 + col;
        out[           pix] = r0*hf;
        out[ 65536 +   pix] = r1*hf;
        out[131072 +   pix] = r2*hf;
        out[196608 +   pix] = hf;
    }
}

extern "C" void kernel_launch(void* const* d_in, const int* in_sizes, int n_in,
                              void* d_out, int out_size, void* d_ws, size_t ws_size,
                              hipStream_t stream) {
    const float* vertices = (const float*)d_in[0];
    const int*   faces    = (const int*)  d_in[1];
    const float* uv       = (const float*)d_in[2];
    const int*   uvfaces  = (const int*)  d_in[3];
    const float* uvmap    = (const float*)d_in[4];
    float*       out      = (float*)d_out;

    dim3 grid(SIZE);
    render_kernel<<<grid, 1024, 0, stream>>>(vertices, faces, uv, uvfaces, uvmap, out);
}